// Round 2
// baseline (11750.015 us; speedup 1.0000x reference)
//
#include <hip/hip_runtime.h>

// LSTM B=512 T=1024 H=150 I=1 + Linear(150->1) + sigmoid.
// 64 blocks x 1024 threads: pair (g, g+32) splits the gate rows of group g's
// 16 sequences. half0 = cells 0-63 (K-chunks s0,s1; tiles 0-15),
// half1 = cells 64-149 + bias(k150)/x(k151) + out-row(vrow600) (s2,s3,s4; tiles 16-37).
// Per step each half publishes its h-slice to global (L2) and spins on the
// partner's monotonic flag; K-chunks are pure per half so B-fragments are
// entirely LDS (own) or entirely global (partner). Weights pre-scaled by
// -log2e / +2log2e so pointwise needs only exp2 + rcp (7 trans/cell).
//
// ws: [0,256) int flags[64]; [256,+131072) hx0[2][32][16][64] f16;
//     then hx1[2][32][16][96] f16 (kk=cell-64, 86=bias, 87=x, 88-95=pad).

typedef _Float16 half8 __attribute__((ext_vector_type(8)));
typedef float f32x4 __attribute__((ext_vector_type(4)));

#define LOG2E 1.44269504088896340736f
#define TWOLOG2E 2.88539008177792681472f

__global__ void reset_flags(int* f) { f[threadIdx.x] = 0; }

__global__ __launch_bounds__(1024) void lstm_split(
    const float* __restrict__ x,      // [512][1024]
    const float* __restrict__ W_ih,   // [600]
    const float* __restrict__ W_hh,   // [600][150]
    const float* __restrict__ b_ih,   // [600]
    const float* __restrict__ b_hh,   // [600]
    const float* __restrict__ W_out,  // [150]
    const float* __restrict__ b_out,  // [1]
    float* __restrict__ out,          // [512][1024]
    int* __restrict__ flags,
    _Float16* __restrict__ hx0,
    _Float16* __restrict__ hx1)
{
  const int tid  = threadIdx.x;
  const int wid  = tid >> 6;
  const int lane = tid & 63;
  const int q    = lane >> 4;
  const int b    = lane & 15;
  const int bid  = blockIdx.x;
  const int g    = bid & 31;
  const int half = bid >> 5;

  __shared__ __align__(16) _Float16 hbuf[2][16][168];
  __shared__ _Float16 xlds[16][1032];

  int* myflag = &flags[g*2 + half];
  int* pflag  = &flags[g*2 + (half ^ 1)];

  // ---- prologue: zero hbuf, stage x (half1 only) ----
  for (int i = tid; i < 2*16*168; i += 1024)
    (&hbuf[0][0][0])[i] = (_Float16)0.0f;
  if (half) {
    const float4* x4 = (const float4*)(x + (size_t)g * 16 * 1024);
    for (int i = tid; i < 16*256; i += 1024) {
      int row = i >> 8, c4 = i & 255;
      float4 v = x4[row*256 + c4];
      xlds[row][c4*4+0] = (_Float16)v.x;
      xlds[row][c4*4+1] = (_Float16)v.y;
      xlds[row][c4*4+2] = (_Float16)v.z;
      xlds[row][c4*4+3] = (_Float16)v.w;
    }
  }

  // ---- weight fragments (A operand); slot j -> K-chunk s (own chunks first) ----
  const float bo = b_out[0];
  const int ntl = half ? ((wid < 6) ? 2 : 1) : 1;
  half8 wf[2][5];
#pragma unroll
  for (int tl = 0; tl < 2; ++tl) {
#pragma unroll
    for (int j = 0; j < 5; ++j) wf[tl][j] = (half8)(_Float16)0.0f;
    if (tl < ntl) {
      const int tg   = half ? (16 + wid + 16*tl) : wid;
      const int vrow = tg*16 + b;          // A-frag row m = lane&15
      const int cell = vrow >> 2, gate = vrow & 3;
      const float alpha = (gate == 2) ? TWOLOG2E : -LOG2E;
#pragma unroll
      for (int j = 0; j < 5; ++j) {
        const int s = half ? ((j >= 3) ? (j - 3) : (j + 2)) : j; // half1: {2,3,4,0,1}
        half8 v;
#pragma unroll
        for (int jj = 0; jj < 8; ++jj) {
          const int k = s*32 + q*8 + jj;
          float w = 0.0f;
          if (vrow == 600) {               // out row rides the MFMA
            if (k < 150)       w = -LOG2E * W_out[k];
            else if (k == 150) w = -LOG2E * bo;
          } else if (cell < 150) {
            const int orow = gate*150 + cell;
            if (k < 150)       w = alpha * W_hh[orow*150 + k];
            else if (k == 150) w = alpha * (b_ih[orow] + b_hh[orow]);
            else if (k == 151) w = alpha * W_ih[orow];
          }
          v[jj] = (_Float16)w;
        }
        wf[tl][j] = v;
      }
    }
  }

  __syncthreads();  // xlds + hbuf-zero visible

  // ---- publish slot 0 (h(-1)=0, bias, x_0) ----
  if (half == 0) {
    _Float16* s0 = hx0 + (size_t)g*16*64;
    if (tid < 512) ((unsigned int*)s0)[tid] = 0u;
  } else {
    _Float16* s0 = hx1 + (size_t)g*16*96;
    _Float16* s1 = hx1 + ((size_t)32 + g)*16*96;
    if (tid < 768) ((unsigned int*)s0)[tid] = 0u;
    if (tid < 16) {
      s0[tid*96 + 86] = (_Float16)1.0f;
      s0[tid*96 + 87] = xlds[tid][0];
      s1[tid*96 + 86] = (_Float16)1.0f;
#pragma unroll
      for (int j = 88; j < 96; ++j) s1[tid*96 + j] = (_Float16)0.0f;
      hbuf[0][tid][150] = (_Float16)1.0f;
      hbuf[1][tid][150] = (_Float16)1.0f;
      hbuf[0][tid][151] = xlds[tid][0];
    }
  }
  __syncthreads();  // drains all waves' global stores (vmcnt 0) before release
  if (tid == 0)
    __hip_atomic_fetch_add(myflag, 1, __ATOMIC_RELEASE, __HIP_MEMORY_SCOPE_AGENT);
  while (__hip_atomic_load(pflag, __ATOMIC_RELAXED, __HIP_MEMORY_SCOPE_AGENT) < 1)
    __builtin_amdgcn_s_sleep(1);
  __builtin_amdgcn_fence(__ATOMIC_ACQUIRE, "agent");

  float cst[2] = {0.f, 0.f};
  const bool is_out = (half == 1) && (wid == 5) && (q == 2); // vrow600: tl=1, reg 0
  float* outp = out + ((size_t)g*16 + b) * 1024;

  for (int t = 0; t <= 1024; ++t) {
    const int cur = t & 1;

    // ---- B fragments: partner (global, issued first) + own (LDS) ----
    half8 bf[5];
    if (half == 0) {
      const _Float16* p = hx1 + (((size_t)cur*32 + g)*16 + b)*96 + q*8;
      bf[2] = *(const half8*)(p);        // s2
      bf[3] = *(const half8*)(p + 32);   // s3
      bf[4] = *(const half8*)(p + 64);   // s4 (incl bias/x/pad)
      bf[0] = *(const half8*)&hbuf[cur][b][q*8];        // s0
      bf[1] = *(const half8*)&hbuf[cur][b][32 + q*8];   // s1
    } else {
      const _Float16* p = hx0 + (((size_t)cur*32 + g)*16 + b)*64 + q*8;
      bf[3] = *(const half8*)(p);        // s0
      bf[4] = *(const half8*)(p + 32);   // s1
      bf[0] = *(const half8*)&hbuf[cur][b][64  + q*8];  // s2
      bf[1] = *(const half8*)&hbuf[cur][b][96  + q*8];  // s3
      bf[2] = *(const half8*)&hbuf[cur][b][128 + q*8];  // s4
    }

    f32x4 acc[2];
#pragma unroll
    for (int tl = 0; tl < 2; ++tl) {
      if (tl < ntl) {
        f32x4 a = {0.f, 0.f, 0.f, 0.f};
#pragma unroll
        for (int j = 0; j < 5; ++j)      // own chunks first; partner latency hidden
          a = __builtin_amdgcn_mfma_f32_16x16x32_f16(wf[tl][j], bf[j], a, 0, 0, 0);
        acc[tl] = a;
      }
    }

    if (is_out && t >= 1)
      outp[t-1] = __builtin_amdgcn_rcpf(1.0f + __builtin_amdgcn_exp2f(acc[1][0]));
    if (t == 1024) break;

    const int nxt = cur ^ 1;
    _Float16* hw = half ? (hx1 + (((size_t)nxt*32 + g)*16 + b)*96 - 64)
                        : (hx0 + (((size_t)nxt*32 + g)*16 + b)*64);
#pragma unroll
    for (int tl = 0; tl < 2; ++tl) {
      if (tl < ntl) {
        const int tg   = half ? (16 + wid + 16*tl) : wid;
        const int cell = tg*4 + q;
        // acc regs: 0=i',1=f',2=g',3=o' (pre-scaled preacts)
        const float ei = __builtin_amdgcn_exp2f(acc[tl][0]);
        const float ef = __builtin_amdgcn_exp2f(acc[tl][1]);
        const float eg = __builtin_amdgcn_exp2f(acc[tl][2]);
        const float eo = __builtin_amdgcn_exp2f(acc[tl][3]);
        const float A  = 1.0f + ei;      // 1/i
        const float F  = 1.0f + ef;      // 1/f
        const float G1 = eg + 1.0f;
        const float Gm = eg - 1.0f;      // g = Gm/G1
        const float AG = A * G1;
        const float num = fmaf(cst[tl], AG, Gm * F);
        const float cn  = num * __builtin_amdgcn_rcpf(F * AG);
        cst[tl] = cn;
        const float ec = __builtin_amdgcn_exp2f(TWOLOG2E * cn);
        const float h  = (ec - 1.0f) *
                         __builtin_amdgcn_rcpf((1.0f + eo) * (ec + 1.0f));
        if (cell < 150) {
          const _Float16 h16 = (_Float16)h;
          hbuf[nxt][b][cell] = h16;
          hw[cell] = h16;                // half1: hw pre-biased by -64
        }
      }
    }
    if (half && tid < 16) {
      const _Float16 xv = (t+1 < 1024) ? xlds[tid][t+1] : (_Float16)0.0f;
      hbuf[nxt][tid][151] = xv;
      (hx1 + (((size_t)nxt*32 + g)*16 + tid)*96)[87] = xv;
    }
    __syncthreads();   // all LDS + global h stores drained
    if (tid == 0)
      __hip_atomic_fetch_add(myflag, 1, __ATOMIC_RELEASE, __HIP_MEMORY_SCOPE_AGENT);
    // wait for partner slot t+1 (published at end of partner's step t)
    while (__hip_atomic_load(pflag, __ATOMIC_RELAXED, __HIP_MEMORY_SCOPE_AGENT) < t + 2)
      __builtin_amdgcn_s_sleep(1);
    __builtin_amdgcn_fence(__ATOMIC_ACQUIRE, "agent");
  }
}

extern "C" void kernel_launch(void* const* d_in, const int* in_sizes, int n_in,
                              void* d_out, int out_size, void* d_ws, size_t ws_size,
                              hipStream_t stream) {
  const float* x     = (const float*)d_in[0];
  const float* W_ih  = (const float*)d_in[1];
  const float* W_hh  = (const float*)d_in[2];
  const float* b_ih  = (const float*)d_in[3];
  const float* b_hh  = (const float*)d_in[4];
  const float* W_out = (const float*)d_in[5];
  const float* b_out = (const float*)d_in[6];

  int* flags     = (int*)d_ws;
  _Float16* hx0  = (_Float16*)((char*)d_ws + 256);
  _Float16* hx1  = (_Float16*)((char*)d_ws + 256 + (size_t)2*32*16*64*2);

  reset_flags<<<1, 64, 0, stream>>>(flags);
  lstm_split<<<64, 1024, 0, stream>>>(
      x, W_ih, W_hh, b_ih, b_hh, W_out, b_out, (float*)d_out, flags, hx0, hx1);
}

// Round 3
// 1017.386 us; speedup vs baseline: 11.5492x; 11.5492x over previous
//
#include <hip/hip_runtime.h>

// LSTM B=512 T=1024 H=150 I=1 + Linear(150->1) + sigmoid.
// 32 blocks x 768 threads (12 waves, 3/SIMD). Block owns 16 sequences.
// M = 640 virtual rows, vrow = 4*cell+gate (cell-major), 38 MFMA tiles of 16;
//   vrow 600 carries W_out (out preact rides the MFMA).
// K = 160: k<150 = h (f16, LDS double-buffered), k=150 = 1.0 (bias col),
//   k=151 = x_t, k>=152 = zero pad.
// Weights pre-scaled by -log2e (i,f,o + out row) or +2log2e (g rows) so the
//   pointwise needs only exp2 + rcp (5 exp2 + 2 rcp per cell).
// Tile ownership: wave w owns {w, 12+w, 24+w}; wave 0 adds tile 36, wave 5
//   adds tile 37 (SIMD loads 10/10/9/9 -> balanced trans work).

typedef _Float16 half8 __attribute__((ext_vector_type(8)));
typedef float f32x4 __attribute__((ext_vector_type(4)));

#define LOG2E 1.44269504088896340736f
#define TWOLOG2E 2.88539008177792681472f

__global__ __launch_bounds__(768, 3) void lstm_kernel(
    const float* __restrict__ x,      // [512][1024]
    const float* __restrict__ W_ih,   // [600]
    const float* __restrict__ W_hh,   // [600][150]
    const float* __restrict__ b_ih,   // [600]
    const float* __restrict__ b_hh,   // [600]
    const float* __restrict__ W_out,  // [150]
    const float* __restrict__ b_out,  // [1]
    float* __restrict__ out)          // [512][1024]
{
  const int tid  = threadIdx.x;
  const int wid  = tid >> 6;
  const int lane = tid & 63;
  const int q    = lane >> 4;   // k-subchunk for A/B frags; cell offset for D
  const int b    = lane & 15;   // batch col (B/D); A-frag row m
  const int bid  = blockIdx.x;

  // stride 168 f16 = 336 B: b128 panel reads are bank-uniform (8/bank min)
  __shared__ __align__(16) _Float16 hbuf[2][16][168];
  __shared__ _Float16 xlds[16][1032];

  // ---- prologue: zero hbuf, stage x as f16 ----
  for (int i = tid; i < 2*16*168; i += 768)
    (&hbuf[0][0][0])[i] = (_Float16)0.0f;
  {
    const float4* x4 = (const float4*)(x + (size_t)bid * 16 * 1024);
    for (int i = tid; i < 16*256; i += 768) {
      int row = i >> 8, c4 = i & 255;
      float4 v = x4[row*256 + c4];
      xlds[row][c4*4+0] = (_Float16)v.x;
      xlds[row][c4*4+1] = (_Float16)v.y;
      xlds[row][c4*4+2] = (_Float16)v.z;
      xlds[row][c4*4+3] = (_Float16)v.w;
    }
  }
  __syncthreads();
  if (tid < 32) hbuf[tid>>4][tid&15][150] = (_Float16)1.0f;  // bias column
  if (tid < 16) hbuf[0][tid][151] = xlds[tid][0];            // x_0
  __syncthreads();

  // ---- tile ownership ----
  const int ntl = (wid == 0 || wid == 5) ? 4 : 3;
  int tiles[4];
  tiles[0] = wid; tiles[1] = 12 + wid; tiles[2] = 24 + wid;
  tiles[3] = (wid == 0) ? 36 : 37;   // only used when ntl==4

  // ---- weight fragments (A operand): up to 4 tiles x 5 K-chunks = 80 VGPR ----
  const float bo = b_out[0];
  half8 wf[4][5];
#pragma unroll
  for (int tl = 0; tl < 4; ++tl) {
#pragma unroll
    for (int s = 0; s < 5; ++s) wf[tl][s] = (half8)(_Float16)0.0f;
    if (tl < ntl) {
      const int tg   = tiles[tl];
      const int vrow = tg*16 + b;     // A-frag: m = lane&15
      const int cell = vrow >> 2, gate = vrow & 3;
      const float alpha = (gate == 2) ? TWOLOG2E : -LOG2E;
#pragma unroll
      for (int s = 0; s < 5; ++s) {
        half8 v;
#pragma unroll
        for (int j = 0; j < 8; ++j) {
          const int k = s*32 + q*8 + j;  // same (q,j)->k map as B frags
          float w = 0.0f;
          if (vrow == 600) {             // out row
            if (k < 150)       w = -LOG2E * W_out[k];
            else if (k == 150) w = -LOG2E * bo;
          } else if (cell < 150) {
            const int orow = gate*150 + cell;
            if (k < 150)       w = alpha * W_hh[orow*150 + k];
            else if (k == 150) w = alpha * (b_ih[orow] + b_hh[orow]);
            else if (k == 151) w = alpha * W_ih[orow];
          }
          v[j] = (_Float16)w;
        }
        wf[tl][s] = v;
      }
    }
  }

  float cst[4] = {0.f, 0.f, 0.f, 0.f};
  const bool is_x   = (wid == 11) && (q == 3);
  const bool is_out = (wid == 5)  && (q == 2);  // vrow 600 -> tile 37 (tl=3), reg 0
  float* outp = out + ((size_t)bid*16 + b) * 1024;

  int cur = 0;
  for (int t = 0; t <= 1024; ++t) {
    _Float16 xv = (_Float16)0.0f;
    if (is_x && t < 1023) xv = xlds[b][t+1];   // issued early, used post-pointwise

    half8 bf[5];
#pragma unroll
    for (int s = 0; s < 5; ++s)
      bf[s] = *(const half8*)&hbuf[cur][b][s*32 + q*8];

    f32x4 acc[4];
#pragma unroll
    for (int tl = 0; tl < 4; ++tl) {
      if (tl < ntl) {
        f32x4 a = {0.f, 0.f, 0.f, 0.f};
#pragma unroll
        for (int s = 0; s < 5; ++s)
          a = __builtin_amdgcn_mfma_f32_16x16x32_f16(wf[tl][s], bf[s], a, 0, 0, 0);
        acc[tl] = a;
      }
    }

    // out_{t-1} = sigmoid(Wout.h_{t-1} + b_out); acc pre-scaled by -log2e
    if (is_out && t >= 1)
      outp[t-1] = __builtin_amdgcn_rcpf(1.0f + __builtin_amdgcn_exp2f(acc[3][0]));
    if (t == 1024) break;

    const int nxt = cur ^ 1;
#pragma unroll
    for (int tl = 0; tl < 4; ++tl) {
      if (tl < ntl) {
        const int cellg = tiles[tl]*4 + q;
        // acc regs: 0=i',1=f',2=g',3=o' (pre-scaled preacts)
        const float ei = __builtin_amdgcn_exp2f(acc[tl][0]);
        const float ef = __builtin_amdgcn_exp2f(acc[tl][1]);
        const float eg = __builtin_amdgcn_exp2f(acc[tl][2]);
        const float eo = __builtin_amdgcn_exp2f(acc[tl][3]);
        const float A  = 1.0f + ei;     // 1/i
        const float F  = 1.0f + ef;     // 1/f
        const float G1 = eg + 1.0f;
        const float Gm = eg - 1.0f;     // g = Gm/G1
        const float AG = A * G1;
        const float num = fmaf(cst[tl], AG, Gm * F);     // c*A*G1 + Gm*F
        const float cn  = num * __builtin_amdgcn_rcpf(F * AG);
        cst[tl] = cn;
        const float ec = __builtin_amdgcn_exp2f(TWOLOG2E * cn);
        const float h  = (ec - 1.0f) *
                         __builtin_amdgcn_rcpf((1.0f + eo) * (ec + 1.0f)); // o*tanh(c)
        if (cellg < 150) hbuf[nxt][b][cellg] = (_Float16)h;
      }
    }
    if (is_x && t < 1023) hbuf[nxt][b][151] = xv;  // x_{t+1}
    __syncthreads();
    cur = nxt;
  }
}

extern "C" void kernel_launch(void* const* d_in, const int* in_sizes, int n_in,
                              void* d_out, int out_size, void* d_ws, size_t ws_size,
                              hipStream_t stream) {
  const float* x     = (const float*)d_in[0];
  const float* W_ih  = (const float*)d_in[1];
  const float* W_hh  = (const float*)d_in[2];
  const float* b_ih  = (const float*)d_in[3];
  const float* b_hh  = (const float*)d_in[4];
  const float* W_out = (const float*)d_in[5];
  const float* b_out = (const float*)d_in[6];
  lstm_kernel<<<dim3(32), dim3(768), 0, stream>>>(
      x, W_ih, W_hh, b_ih, b_hh, W_out, b_out, (float*)d_out);
}